// Round 10
// baseline (168.341 us; speedup 1.0000x reference)
//
#include <hip/hip_runtime.h>
#include <hip/hip_bf16.h>

#define DF 128
#define BSH 5                 // bucket = dst >> 5  (32 nodes / bucket)
#define BNODES 32
#define NBMAX 1600            // max buckets (50000/32 = 1563)
#define CHUNK 1024            // edges per fused hist/sort block (782 blocks, ~3/CU)
#define BMAX 800              // max edge chunks (782 here)
#define TILE 2048             // edges per aggregation LDS tile (bucket ~512)
#define ASTRIDE 64            // uints per abuf row
#define SRCMASK 0x07ffffffu   // src in low 27 bits, dstLocal in bits 27..31

typedef __attribute__((ext_vector_type(8))) short short8;
typedef __attribute__((ext_vector_type(4))) float floatx4;

__device__ __forceinline__ ushort f2bf(float f) {
    __hip_bfloat16 h = __float2bfloat16(f);   // RNE
    return *reinterpret_cast<ushort*>(&h);
}

// ---------------------------------------------------------------------------
// K1: [0,B_) fused hist+scan+sort edge blocks | [B_,B_+16) weight convert |
// rest x convert (8 float4 per thread).
// Edge block: histogram 1024 edges over 1563 buckets, in-block exclusive
// scan, write row prefix as USHORT to rowoffs[j][*], LDS bucket-sort, write
// own contiguous pairs region [j*CHUNK, j*CHUNK+cnt) coalesced.
// Fat grid (~3 blocks/CU) so the serial per-block phases overlap across
// co-resident blocks (R7 vs R9: fatter edge grid is strictly better).
// ---------------------------------------------------------------------------
__global__ __launch_bounds__(256) void prep_kernel(
    const float* __restrict__ x, ushort* __restrict__ xbf, int n4,
    const float* __restrict__ W1, const float* __restrict__ W2,
    const float* __restrict__ b1, const float* __restrict__ b2,
    ushort* __restrict__ w1bf, ushort* __restrict__ w2bf, float* __restrict__ bias,
    const int* __restrict__ src, const int* __restrict__ dst,
    ushort* __restrict__ rowoffs, uint* __restrict__ pairs,
    int n_edges, int B_, int nb)
{
    __shared__ int  h[NBMAX];       // hist -> prefix -> cursors (6.4 KB)
    __shared__ int  sd[256];
    __shared__ uint stage[CHUNK];   // 4 KB
    int bid = blockIdx.x;
    int tid = threadIdx.x;

    if (bid < B_) {
        int base = bid * CHUNK;
        int cnt = n_edges - base; if (cnt > CHUNK) cnt = CHUNK;

        for (int j = tid; j < nb; j += 256) h[j] = 0;
        __syncthreads();

        // load edges to regs + LDS histogram
        int d[CHUNK / 256], s[CHUNK / 256];
#pragma unroll
        for (int k = 0; k < CHUNK / 256; ++k) {
            int i = k * 256 + tid;
            bool ok = i < cnt;
            d[k] = ok ? dst[base + i] : -1;
            s[k] = ok ? src[base + i] : 0;
            if (ok) atomicAdd(&h[d[k] >> BSH], 1);
        }
        __syncthreads();

        // in-block exclusive scan of nb+1 entries (thread t owns 7)
        int b0 = tid * 7;
        int tv[7];
        int ls = 0;
#pragma unroll
        for (int k = 0; k < 7; ++k) {
            int idx = b0 + k;
            tv[k] = (idx < nb) ? h[idx] : 0;
            ls += tv[k];
        }
        sd[tid] = ls;
        __syncthreads();
        for (int off = 1; off < 256; off <<= 1) {
            int u = (tid >= off) ? sd[tid - off] : 0;
            __syncthreads();
            sd[tid] += u;
            __syncthreads();
        }
        int run = sd[tid] - ls;

        // write prefix: LDS cursors + global rowoffs row (incl. entry nb = cnt)
        ushort* ro = rowoffs + (size_t)bid * (nb + 1);
#pragma unroll
        for (int k = 0; k < 7; ++k) {
            int idx = b0 + k;
            if (idx < nb) h[idx] = run;
            if (idx <= nb) ro[idx] = (ushort)run;
            run += tv[k];
        }
        __syncthreads();   // prefix stable before cursor atomics

        // sort into LDS stage, then coalesced write of own region
#pragma unroll
        for (int k = 0; k < CHUNK / 256; ++k) {
            if (d[k] >= 0) {
                int p = atomicAdd(&h[d[k] >> BSH], 1);
                stage[p] = (uint)s[k] | ((uint)(d[k] & (BNODES - 1)) << 27);
            }
        }
        __syncthreads();
        for (int i = tid; i < cnt; i += 256)
            pairs[base + i] = stage[i];
    } else if (bid < B_ + 16) {
        int i0 = (bid - B_) * 1024;
#pragma unroll
        for (int k = 0; k < 4; ++k) {
            int i = i0 + k * 256 + tid;
            if (i < DF * DF) {
                w1bf[i] = f2bf(W1[i]);
                w2bf[i] = f2bf(W2[i]);
            }
        }
        if (bid == B_ && tid < DF) bias[tid] = b1[tid] + b2[tid];
    } else {
        int base = (bid - B_ - 16) * 2048 + tid;
#pragma unroll
        for (int k = 0; k < 8; ++k) {
            int i = base + k * 256;
            if (i < n4) {
                float4 v = reinterpret_cast<const float4*>(x)[i];
                ushort4 o;
                o.x = f2bf(v.x); o.y = f2bf(v.y); o.z = f2bf(v.z); o.w = f2bf(v.w);
                reinterpret_cast<ushort4*>(xbf)[i] = o;
            }
        }
    }
}

// ---------------------------------------------------------------------------
// K2: fused aggregate + MFMA GEMM. Block = 32 nodes = 1 bucket, 256 threads,
// 1563 blocks, 7 blocks/CU (~22.6 KB LDS). Run j for bucket blk:
// start = j*CHUNK + rowoffs[j][blk], count = rowoffs[j][blk+1]-rowoffs[j][blk].
// 10-step binary search locates run per tile element. 16-deep gather. MFMA.
// ---------------------------------------------------------------------------
__global__ __launch_bounds__(256, 7) void agg_gemm_kernel(
    const ushort* __restrict__ xbf, const uint* __restrict__ pairs,
    const ushort* __restrict__ rowoffs,
    const ushort* __restrict__ w1, const ushort* __restrict__ w2,
    const float* __restrict__ bias, float* __restrict__ out,
    int n_nodes, int B_, int nb)
{
    __shared__ uint sorted[TILE];               // 8 KB (byte offsets, src<<8)
    __shared__ uint abuf[BNODES * ASTRIDE];     // 8 KB
    __shared__ int  rstart[BMAX];               // 3.2 KB
    __shared__ int  rexcl[BMAX + 1];            // 3.2 KB
    __shared__ int hcnt[BNODES];
    __shared__ int hoff[BNODES + 1];
    __shared__ int hcur[BNODES];

    int blk  = blockIdx.x;      // == bucket index
    int node0 = blk * BNODES;
    int wave = threadIdx.x >> 6;
    int lane = threadIdx.x & 63;
    int NBP = nb + 1;

    // runs: chunk j's cell for this bucket (independent per-row offsets)
    for (int j = threadIdx.x; j < B_; j += 256) {
        const ushort* ro = rowoffs + (size_t)j * NBP + blk;
        int s = ro[0];
        int e = ro[1];
        rstart[j] = j * CHUNK + s;
        rexcl[j]  = e - s;     // count (temp)
    }
    __syncthreads();
    if (threadIdx.x < 64) {     // wave 0: exclusive scan of <=832 counts
        int b0 = lane * 13;
        int tv[13];
        int ls = 0;
#pragma unroll
        for (int k = 0; k < 13; ++k) {
            int idx = b0 + k;
            tv[k] = (idx < B_) ? rexcl[idx] : 0;
            ls += tv[k];
        }
        int si = ls;
#pragma unroll
        for (int off = 1; off < 64; off <<= 1) {
            int u = __shfl_up(si, off);
            if (lane >= off) si += u;
        }
        int run = si - ls;
#pragma unroll
        for (int k = 0; k < 13; ++k) {
            int idx = b0 + k;
            if (idx < B_) rexcl[idx] = run;
            run += tv[k];
        }
        if (lane == 63) rexcl[B_] = run;   // total
    }
    __syncthreads();
    int total = rexcl[B_];

    const char* xu = (const char*)xbf;
    uint lane4 = (uint)lane << 2;

    float2 acc[8];
#pragma unroll
    for (int i = 0; i < 8; ++i) acc[i] = make_float2(0.f, 0.f);

    for (int t0 = 0; t0 < total; t0 += TILE) {
        int cnt = total - t0; if (cnt > TILE) cnt = TILE;

        if (threadIdx.x < BNODES) hcnt[threadIdx.x] = 0;
        __syncthreads();

        // pass A: binary-search run, read pair into registers, node-histogram
        uint pk_[TILE / 256];
#pragma unroll
        for (int k = 0; k < TILE / 256; ++k) {
            int i = threadIdx.x + k * 256;
            if (i < cnt) {
                int t = t0 + i;
                int lo = 0, hi = B_;
                while (lo + 1 < hi) {
                    int mid = (lo + hi) >> 1;
                    if (rexcl[mid] <= t) lo = mid; else hi = mid;
                }
                uint pk = pairs[rstart[lo] + (t - rexcl[lo])];
                pk_[k] = pk;
                atomicAdd(&hcnt[pk >> 27], 1);
            }
        }
        __syncthreads();

        // 32-entry exclusive scan by wave 0 via shfl
        if (threadIdx.x < 64) {
            int v = (lane < BNODES) ? hcnt[lane] : 0;
#pragma unroll
            for (int off = 1; off < BNODES; off <<= 1) {
                int u = __shfl_up(v, off);
                if (lane >= off) v += u;
            }
            if (lane < BNODES) {
                hoff[lane + 1] = v;
                hcur[lane] = v - hcnt[lane];
            }
            if (lane == 0) hoff[0] = 0;
        }
        __syncthreads();

        // pass B: scatter pre-scaled row byte-offsets, node-sorted
#pragma unroll
        for (int k = 0; k < TILE / 256; ++k) {
            int i = threadIdx.x + k * 256;
            if (i < cnt) {
                uint pk = pk_[k];
                int p = atomicAdd(&hcur[pk >> 27], 1);
                sorted[p] = (pk & SRCMASK) << 8;   // byte offset of 256B row
            }
        }
        __syncthreads();

        // wave owns nodes wave*8 .. wave*8+7; 16-deep independent gathers
#pragma unroll
        for (int i = 0; i < 8; ++i) {
            int nl = wave * 8 + i;
            int j0 = hoff[nl], j1 = hoff[nl + 1];
            float2 a = acc[i];
            int j = j0;
            for (; j + 15 < j1; j += 16) {
                uint u[16];
#pragma unroll
                for (int k = 0; k < 16; ++k)
                    u[k] = *(const uint*)(xu + (size_t)(sorted[j + k] + lane4));
#pragma unroll
                for (int k = 0; k < 16; ++k) {
                    a.x += __uint_as_float(u[k] << 16);
                    a.y += __uint_as_float(u[k] & 0xffff0000u);
                }
            }
            for (; j + 3 < j1; j += 4) {
                uint u0 = *(const uint*)(xu + (size_t)(sorted[j + 0] + lane4));
                uint u1 = *(const uint*)(xu + (size_t)(sorted[j + 1] + lane4));
                uint u2 = *(const uint*)(xu + (size_t)(sorted[j + 2] + lane4));
                uint u3 = *(const uint*)(xu + (size_t)(sorted[j + 3] + lane4));
                a.x += __uint_as_float(u0 << 16) + __uint_as_float(u1 << 16)
                     + __uint_as_float(u2 << 16) + __uint_as_float(u3 << 16);
                a.y += __uint_as_float(u0 & 0xffff0000u) + __uint_as_float(u1 & 0xffff0000u)
                     + __uint_as_float(u2 & 0xffff0000u) + __uint_as_float(u3 & 0xffff0000u);
            }
            for (; j < j1; ++j) {
                uint u = *(const uint*)(xu + (size_t)(sorted[j] + lane4));
                a.x += __uint_as_float(u << 16);
                a.y += __uint_as_float(u & 0xffff0000u);
            }
            acc[i] = a;
        }
        __syncthreads();   // protect sorted/hist before next tile
    }

    // stage aggregated rows as bf16 into LDS
#pragma unroll
    for (int i = 0; i < 8; ++i) {
        int nl = wave * 8 + i;
        abuf[nl * ASTRIDE + lane] =
            (uint)f2bf(acc[i].x) | ((uint)f2bf(acc[i].y) << 16);
    }
    __syncthreads();

    // ---- MFMA phase: 2 waves per 16-row group; each does 4 of 8 o-tiles ----
    int quad = lane >> 4;
    int m    = lane & 15;
    int rg   = wave >> 1;          // row group 0..1
    int half = wave & 1;           // which 4 o-tiles
    int rowL = rg * 16 + m;
    int rowG = node0 + rowL;
    int rowC = (rowG < n_nodes) ? rowG : (n_nodes - 1);   // clamp loads

    short8 xa[4], aa[4];
#pragma unroll
    for (int ks = 0; ks < 4; ++ks) {
        xa[ks] = *reinterpret_cast<const short8*>(xbf + (size_t)rowC * DF + ks * 32 + quad * 8);
        aa[ks] = *reinterpret_cast<const short8*>(&abuf[rowL * ASTRIDE + ks * 16 + quad * 4]);
    }

    int nbase = node0 + rg * 16;
#pragma unroll
    for (int oi = 0; oi < 4; ++oi) {
        int ot = half * 4 + oi;
        int o = ot * 16 + m;
        floatx4 c = {0.f, 0.f, 0.f, 0.f};
#pragma unroll
        for (int ks = 0; ks < 4; ++ks) {
            short8 bf1 = *reinterpret_cast<const short8*>(w1 + (size_t)o * DF + ks * 32 + quad * 8);
            short8 bf2 = *reinterpret_cast<const short8*>(w2 + (size_t)o * DF + ks * 32 + quad * 8);
            c = __builtin_amdgcn_mfma_f32_16x16x32_bf16(xa[ks], bf1, c, 0, 0, 0);
            c = __builtin_amdgcn_mfma_f32_16x16x32_bf16(aa[ks], bf2, c, 0, 0, 0);
        }
        float bv = bias[o];
#pragma unroll
        for (int r = 0; r < 4; ++r) {
            int row = nbase + quad * 4 + r;
            if (row < n_nodes) out[(size_t)row * DF + o] = c[r] + bv;
        }
    }
}

extern "C" void kernel_launch(void* const* d_in, const int* in_sizes, int n_in,
                              void* d_out, int out_size, void* d_ws, size_t ws_size,
                              hipStream_t stream) {
    const float* x  = (const float*)d_in[0];
    const float* W1 = (const float*)d_in[1];
    const float* b1 = (const float*)d_in[2];
    const float* W2 = (const float*)d_in[3];
    const float* b2 = (const float*)d_in[4];
    const int* esrc = (const int*)d_in[5];
    const int* edst = (const int*)d_in[6];
    float* out = (float*)d_out;

    int n_nodes = in_sizes[0] / DF;
    int n_edges = in_sizes[5];

    int nb = (n_nodes + BNODES - 1) >> BSH;       // buckets (1563)
    int B_ = (n_edges + CHUNK - 1) / CHUNK;       // edge chunks (782 <= BMAX)

    auto rnd16 = [](size_t v) { return (v + 15) & ~(size_t)15; };

    char* ws = (char*)d_ws;
    ushort* xbf     = (ushort*)ws;               ws += rnd16((size_t)n_nodes * DF * 2);
    ushort* w1bf    = (ushort*)ws;               ws += rnd16((size_t)DF * DF * 2);
    ushort* w2bf    = (ushort*)ws;               ws += rnd16((size_t)DF * DF * 2);
    float*  bias    = (float*)ws;                ws += rnd16((size_t)DF * 4);
    ushort* rowoffs = (ushort*)ws;               ws += rnd16((size_t)B_ * (nb + 1) * 2);
    uint*   pairs   = (uint*)ws;

    int n4 = n_nodes * DF / 4;                    // 1.6M float4s
    int CB = (n4 + 2047) / 2048;                  // convert blocks (782)
    int prep_blocks = B_ + 16 + CB;               // 1580 total
    prep_kernel<<<prep_blocks, 256, 0, stream>>>(
        x, xbf, n4, W1, W2, b1, b2, w1bf, w2bf, bias,
        esrc, edst, rowoffs, pairs, n_edges, B_, nb);

    agg_gemm_kernel<<<nb, 256, 0, stream>>>(
        xbf, pairs, rowoffs, w1bf, w2bf, bias, out, n_nodes, B_, nb);
}

// Round 11
// 151.475 us; speedup vs baseline: 1.1113x; 1.1113x over previous
//
#include <hip/hip_runtime.h>
#include <hip/hip_bf16.h>

#define DF 128
#define BSH 5                 // bucket = dst >> 5  (32 nodes / bucket)
#define BNODES 32
#define NBMAX 1600            // max buckets (50000/32 = 1563)
#define CHUNK 2048            // edges per fused hist/sort block (391 blocks)
#define BMAX 400              // max edge chunks (391 here)
#define TILE 2048             // edges per aggregation LDS tile (bucket ~512)
#define ASTRIDE 64            // uints per abuf row
#define SRCMASK 0x07ffffffu   // src in low 27 bits, dstLocal in bits 27..31

typedef __attribute__((ext_vector_type(8))) short short8;
typedef __attribute__((ext_vector_type(4))) float floatx4;

__device__ __forceinline__ ushort f2bf(float f) {
    __hip_bfloat16 h = __float2bfloat16(f);   // RNE
    return *reinterpret_cast<ushort*>(&h);
}

// ---------------------------------------------------------------------------
// K1: [0,B_) fused hist+scan+sort blocks | [B_,B_+64) weight convert |
// rest x convert.
// With block-major pairs layout, chunk j's output region starts at exactly
// j*CHUNK and its internal layout depends only on chunk j's own histogram
// prefix: each edge block independently histograms its 2048 edges, scans the
// 1563-bucket row in-block, writes the row prefix to rowoffs[j][*] (for agg),
// sorts edges by bucket into LDS, and writes its contiguous pairs region
// coalesced. No global scan, no cross-block coupling, no fences.
// ---------------------------------------------------------------------------
__global__ __launch_bounds__(256) void prep_kernel(
    const float* __restrict__ x, ushort* __restrict__ xbf, int n4,
    const float* __restrict__ W1, const float* __restrict__ W2,
    const float* __restrict__ b1, const float* __restrict__ b2,
    ushort* __restrict__ w1bf, ushort* __restrict__ w2bf, float* __restrict__ bias,
    const int* __restrict__ src, const int* __restrict__ dst,
    int* __restrict__ rowoffs, uint* __restrict__ pairs,
    int n_edges, int B_, int nb)
{
    __shared__ int  h[NBMAX];       // hist -> prefix -> cursors (6.4 KB)
    __shared__ int  sd[256];
    __shared__ uint stage[CHUNK];   // 8 KB
    int bid = blockIdx.x;
    int tid = threadIdx.x;

    if (bid < B_) {
        int base = bid * CHUNK;
        int cnt = n_edges - base; if (cnt > CHUNK) cnt = CHUNK;

        for (int j = tid; j < nb; j += 256) h[j] = 0;
        __syncthreads();

        // load edges to regs + LDS histogram
        int d[CHUNK / 256], s[CHUNK / 256];
#pragma unroll
        for (int k = 0; k < CHUNK / 256; ++k) {
            int i = k * 256 + tid;
            bool ok = i < cnt;
            d[k] = ok ? dst[base + i] : -1;
            s[k] = ok ? src[base + i] : 0;
            if (ok) atomicAdd(&h[d[k] >> BSH], 1);
        }
        __syncthreads();

        // in-block exclusive scan of nb+1 entries (thread t owns 7)
        int b0 = tid * 7;
        int tv[7];
        int ls = 0;
#pragma unroll
        for (int k = 0; k < 7; ++k) {
            int idx = b0 + k;
            tv[k] = (idx < nb) ? h[idx] : 0;
            ls += tv[k];
        }
        sd[tid] = ls;
        __syncthreads();
        for (int off = 1; off < 256; off <<= 1) {
            int u = (tid >= off) ? sd[tid - off] : 0;
            __syncthreads();
            sd[tid] += u;
            __syncthreads();
        }
        int run = sd[tid] - ls;

        // write prefix: LDS cursors + global rowoffs row (incl. entry nb = cnt)
        int* ro = rowoffs + (size_t)bid * (nb + 1);
#pragma unroll
        for (int k = 0; k < 7; ++k) {
            int idx = b0 + k;
            if (idx < nb) h[idx] = run;
            if (idx <= nb) ro[idx] = run;
            run += tv[k];
        }
        __syncthreads();   // prefix stable before cursor atomics

        // sort into LDS stage, then coalesced write of own region
#pragma unroll
        for (int k = 0; k < CHUNK / 256; ++k) {
            if (d[k] >= 0) {
                int p = atomicAdd(&h[d[k] >> BSH], 1);
                stage[p] = (uint)s[k] | ((uint)(d[k] & (BNODES - 1)) << 27);
            }
        }
        __syncthreads();
        for (int i = tid; i < cnt; i += 256)
            pairs[base + i] = stage[i];
    } else if (bid < B_ + 64) {
        int i = (bid - B_) * 256 + tid;
        if (i < DF * DF) {
            w1bf[i] = f2bf(W1[i]);
            w2bf[i] = f2bf(W2[i]);
        }
        if (i < DF) bias[i] = b1[i] + b2[i];
    } else {
        int i = (bid - B_ - 64) * 256 + tid;
        if (i < n4) {
            float4 v = reinterpret_cast<const float4*>(x)[i];
            ushort4 o;
            o.x = f2bf(v.x); o.y = f2bf(v.y); o.z = f2bf(v.z); o.w = f2bf(v.w);
            reinterpret_cast<ushort4*>(xbf)[i] = o;
        }
    }
}

// ---------------------------------------------------------------------------
// K2: fused aggregate + MFMA GEMM. Block = 32 nodes = 1 bucket, 256 threads,
// 1563 blocks, 8 blocks/CU (~19.6 KB LDS). Run j for bucket blk:
// start = j*CHUNK + rowoffs[j][blk], count = rowoffs[j][blk+1]-rowoffs[j][blk].
// 9-step binary search locates run per tile element. 16-deep gather. MFMA.
// ---------------------------------------------------------------------------
__global__ __launch_bounds__(256, 8) void agg_gemm_kernel(
    const ushort* __restrict__ xbf, const uint* __restrict__ pairs,
    const int* __restrict__ rowoffs,
    const ushort* __restrict__ w1, const ushort* __restrict__ w2,
    const float* __restrict__ bias, float* __restrict__ out,
    int n_nodes, int B_, int nb)
{
    __shared__ uint sorted[TILE];               // 8 KB (byte offsets, src<<8)
    __shared__ uint abuf[BNODES * ASTRIDE];     // 8 KB
    __shared__ int  rstart[BMAX];               // 1.6 KB
    __shared__ int  rexcl[BMAX + 1];            // 1.6 KB
    __shared__ int hcnt[BNODES];
    __shared__ int hoff[BNODES + 1];
    __shared__ int hcur[BNODES];

    int blk  = blockIdx.x;      // == bucket index
    int node0 = blk * BNODES;
    int wave = threadIdx.x >> 6;
    int lane = threadIdx.x & 63;
    int NBP = nb + 1;

    // runs: chunk j's cell for this bucket (independent per-row offsets)
    for (int j = threadIdx.x; j < B_; j += 256) {
        const int* ro = rowoffs + (size_t)j * NBP + blk;
        int s = ro[0];
        int e = ro[1];
        rstart[j] = j * CHUNK + s;
        rexcl[j]  = e - s;     // count (temp)
    }
    __syncthreads();
    if (threadIdx.x < 64) {     // wave 0: exclusive scan of <=448 counts
        int b0 = lane * 7;
        int tv[7];
        int ls = 0;
#pragma unroll
        for (int k = 0; k < 7; ++k) {
            int idx = b0 + k;
            tv[k] = (idx < B_) ? rexcl[idx] : 0;
            ls += tv[k];
        }
        int si = ls;
#pragma unroll
        for (int off = 1; off < 64; off <<= 1) {
            int u = __shfl_up(si, off);
            if (lane >= off) si += u;
        }
        int run = si - ls;
#pragma unroll
        for (int k = 0; k < 7; ++k) {
            int idx = b0 + k;
            if (idx < B_) rexcl[idx] = run;
            run += tv[k];
        }
        if (lane == 63) rexcl[B_] = run;   // total
    }
    __syncthreads();
    int total = rexcl[B_];

    const char* xu = (const char*)xbf;
    uint lane4 = (uint)lane << 2;

    float2 acc[8];
#pragma unroll
    for (int i = 0; i < 8; ++i) acc[i] = make_float2(0.f, 0.f);

    for (int t0 = 0; t0 < total; t0 += TILE) {
        int cnt = total - t0; if (cnt > TILE) cnt = TILE;

        if (threadIdx.x < BNODES) hcnt[threadIdx.x] = 0;
        __syncthreads();

        // pass A: binary-search run, read pair into registers, node-histogram
        uint pk_[TILE / 256];
#pragma unroll
        for (int k = 0; k < TILE / 256; ++k) {
            int i = threadIdx.x + k * 256;
            if (i < cnt) {
                int t = t0 + i;
                int lo = 0, hi = B_;
                while (lo + 1 < hi) {
                    int mid = (lo + hi) >> 1;
                    if (rexcl[mid] <= t) lo = mid; else hi = mid;
                }
                uint pk = pairs[rstart[lo] + (t - rexcl[lo])];
                pk_[k] = pk;
                atomicAdd(&hcnt[pk >> 27], 1);
            }
        }
        __syncthreads();

        // 32-entry exclusive scan by wave 0 via shfl
        if (threadIdx.x < 64) {
            int v = (lane < BNODES) ? hcnt[lane] : 0;
#pragma unroll
            for (int off = 1; off < BNODES; off <<= 1) {
                int u = __shfl_up(v, off);
                if (lane >= off) v += u;
            }
            if (lane < BNODES) {
                hoff[lane + 1] = v;
                hcur[lane] = v - hcnt[lane];
            }
            if (lane == 0) hoff[0] = 0;
        }
        __syncthreads();

        // pass B: scatter pre-scaled row byte-offsets, node-sorted
#pragma unroll
        for (int k = 0; k < TILE / 256; ++k) {
            int i = threadIdx.x + k * 256;
            if (i < cnt) {
                uint pk = pk_[k];
                int p = atomicAdd(&hcur[pk >> 27], 1);
                sorted[p] = (pk & SRCMASK) << 8;   // byte offset of 256B row
            }
        }
        __syncthreads();

        // wave owns nodes wave*8 .. wave*8+7; 16-deep independent gathers
#pragma unroll
        for (int i = 0; i < 8; ++i) {
            int nl = wave * 8 + i;
            int j0 = hoff[nl], j1 = hoff[nl + 1];
            float2 a = acc[i];
            int j = j0;
            for (; j + 15 < j1; j += 16) {
                uint u[16];
#pragma unroll
                for (int k = 0; k < 16; ++k)
                    u[k] = *(const uint*)(xu + (size_t)(sorted[j + k] + lane4));
#pragma unroll
                for (int k = 0; k < 16; ++k) {
                    a.x += __uint_as_float(u[k] << 16);
                    a.y += __uint_as_float(u[k] & 0xffff0000u);
                }
            }
            for (; j + 3 < j1; j += 4) {
                uint u0 = *(const uint*)(xu + (size_t)(sorted[j + 0] + lane4));
                uint u1 = *(const uint*)(xu + (size_t)(sorted[j + 1] + lane4));
                uint u2 = *(const uint*)(xu + (size_t)(sorted[j + 2] + lane4));
                uint u3 = *(const uint*)(xu + (size_t)(sorted[j + 3] + lane4));
                a.x += __uint_as_float(u0 << 16) + __uint_as_float(u1 << 16)
                     + __uint_as_float(u2 << 16) + __uint_as_float(u3 << 16);
                a.y += __uint_as_float(u0 & 0xffff0000u) + __uint_as_float(u1 & 0xffff0000u)
                     + __uint_as_float(u2 & 0xffff0000u) + __uint_as_float(u3 & 0xffff0000u);
            }
            for (; j < j1; ++j) {
                uint u = *(const uint*)(xu + (size_t)(sorted[j] + lane4));
                a.x += __uint_as_float(u << 16);
                a.y += __uint_as_float(u & 0xffff0000u);
            }
            acc[i] = a;
        }
        __syncthreads();   // protect sorted/hist before next tile
    }

    // stage aggregated rows as bf16 into LDS
#pragma unroll
    for (int i = 0; i < 8; ++i) {
        int nl = wave * 8 + i;
        abuf[nl * ASTRIDE + lane] =
            (uint)f2bf(acc[i].x) | ((uint)f2bf(acc[i].y) << 16);
    }
    __syncthreads();

    // ---- MFMA phase: 2 waves per 16-row group; each does 4 of 8 o-tiles ----
    int quad = lane >> 4;
    int m    = lane & 15;
    int rg   = wave >> 1;          // row group 0..1
    int half = wave & 1;           // which 4 o-tiles
    int rowL = rg * 16 + m;
    int rowG = node0 + rowL;
    int rowC = (rowG < n_nodes) ? rowG : (n_nodes - 1);   // clamp loads

    short8 xa[4], aa[4];
#pragma unroll
    for (int ks = 0; ks < 4; ++ks) {
        xa[ks] = *reinterpret_cast<const short8*>(xbf + (size_t)rowC * DF + ks * 32 + quad * 8);
        aa[ks] = *reinterpret_cast<const short8*>(&abuf[rowL * ASTRIDE + ks * 16 + quad * 4]);
    }

    int nbase = node0 + rg * 16;
#pragma unroll
    for (int oi = 0; oi < 4; ++oi) {
        int ot = half * 4 + oi;
        int o = ot * 16 + m;
        floatx4 c = {0.f, 0.f, 0.f, 0.f};
#pragma unroll
        for (int ks = 0; ks < 4; ++ks) {
            short8 bf1 = *reinterpret_cast<const short8*>(w1 + (size_t)o * DF + ks * 32 + quad * 8);
            short8 bf2 = *reinterpret_cast<const short8*>(w2 + (size_t)o * DF + ks * 32 + quad * 8);
            c = __builtin_amdgcn_mfma_f32_16x16x32_bf16(xa[ks], bf1, c, 0, 0, 0);
            c = __builtin_amdgcn_mfma_f32_16x16x32_bf16(aa[ks], bf2, c, 0, 0, 0);
        }
        float bv = bias[o];
#pragma unroll
        for (int r = 0; r < 4; ++r) {
            int row = nbase + quad * 4 + r;
            if (row < n_nodes) out[(size_t)row * DF + o] = c[r] + bv;
        }
    }
}

extern "C" void kernel_launch(void* const* d_in, const int* in_sizes, int n_in,
                              void* d_out, int out_size, void* d_ws, size_t ws_size,
                              hipStream_t stream) {
    const float* x  = (const float*)d_in[0];
    const float* W1 = (const float*)d_in[1];
    const float* b1 = (const float*)d_in[2];
    const float* W2 = (const float*)d_in[3];
    const float* b2 = (const float*)d_in[4];
    const int* esrc = (const int*)d_in[5];
    const int* edst = (const int*)d_in[6];
    float* out = (float*)d_out;

    int n_nodes = in_sizes[0] / DF;
    int n_edges = in_sizes[5];

    int nb = (n_nodes + BNODES - 1) >> BSH;       // buckets (1563)
    int B_ = (n_edges + CHUNK - 1) / CHUNK;       // edge chunks (391 <= BMAX-1)

    auto rnd16 = [](size_t v) { return (v + 15) & ~(size_t)15; };

    char* ws = (char*)d_ws;
    ushort* xbf     = (ushort*)ws;               ws += rnd16((size_t)n_nodes * DF * 2);
    ushort* w1bf    = (ushort*)ws;               ws += rnd16((size_t)DF * DF * 2);
    ushort* w2bf    = (ushort*)ws;               ws += rnd16((size_t)DF * DF * 2);
    float*  bias    = (float*)ws;                ws += rnd16((size_t)DF * 4);
    int*    rowoffs = (int*)ws;                  ws += rnd16((size_t)B_ * (nb + 1) * 4);
    uint*   pairs   = (uint*)ws;

    int n4 = n_nodes * DF / 4;
    int prep_blocks = B_ + 64 + (n4 + 255) / 256;
    prep_kernel<<<prep_blocks, 256, 0, stream>>>(
        x, xbf, n4, W1, W2, b1, b2, w1bf, w2bf, bias,
        esrc, edst, rowoffs, pairs, n_edges, B_, nb);

    agg_gemm_kernel<<<nb, 256, 0, stream>>>(
        xbf, pairs, rowoffs, w1bf, w2bf, bias, out, n_nodes, B_, nb);
}